// Round 1
// baseline (67.044 us; speedup 1.0000x reference)
//
#include <hip/hip_runtime.h>

// out[l*16+p, h, w] = sum_{j,k1,k2} mask(w,k1,k2) * t4[p,j,(h-1)%14, w+k1+k2-2] * w_conv[l,j,k1,k2]
// t4[p,j,o,n] = sum_q w_mix[p,q] * x[q*8+j, o, n]
// mask: (0 <= w+k2-1 < 14) && (0 <= w+k1+k2-2 < 14)

__global__ __launch_bounds__(256) void fused_mix_unfold_conv(
    const float* __restrict__ x,       // (512,14,14)
    const float* __restrict__ w_conv,  // (32,8,3,3)
    const float* __restrict__ w_mix,   // (16,64)
    float* __restrict__ out)           // (512,14,14)
{
    const int o   = blockIdx.x;   // pre-roll H row, 0..13
    const int lh  = blockIdx.y;   // l-half: l in [lh*16, lh*16+16)
    const int tid = threadIdx.x;

    __shared__ float sm_x[512 * 14];      // [ch][n]   28 KB
    __shared__ float sm_t4[8 * 16 * 17];  // [j][p][n] pad-17 so 16 p-lanes hit 16 banks
    __shared__ float sm_wc[16 * 72];      // this block's half of w_conv

    // ---- Phase A: stage x row `o` (float2) + w_conv half ----
    {
        const float2* x2  = (const float2*)x;
        float2* smx2 = (float2*)sm_x;
        #pragma unroll
        for (int i = 0; i < 14; ++i) {
            int idx = tid + i * 256;        // 0..3583 ; sm_x[ch*14 + 2*t7 ..]
            int ch = idx / 7, t7 = idx - ch * 7;
            smx2[idx] = x2[ch * 98 + o * 7 + t7];
        }
        for (int i = tid; i < 1152; i += 256)
            sm_wc[i] = w_conv[lh * 1152 + i];
    }
    __syncthreads();

    // ---- Phase B: t4[p,j,n] for all 16 p (wave-pair split over p-groups) ----
    {
        const int wv   = tid >> 6;
        const int lane = tid & 63;
        const int pgrp = __builtin_amdgcn_readfirstlane(wv & 1); // wave-uniform
        const int jn   = (wv >> 1) * 64 + lane;                  // 0..127, valid <112
        if (jn < 112) {
            const int j = jn / 14;
            const int n = jn - j * 14;
            float acc[8];
            #pragma unroll
            for (int pp = 0; pp < 8; ++pp) acc[pp] = 0.f;
            const float4* wm4 = (const float4*)(w_mix + pgrp * 512); // rows pgrp*8..+8
            #pragma unroll
            for (int q4 = 0; q4 < 16; ++q4) {
                // sm_x[(q*8+j)*14+n] = sm_x[q*112 + jn] : lane-consecutive, conflict-free
                float xv0 = sm_x[(q4 * 4 + 0) * 112 + jn];
                float xv1 = sm_x[(q4 * 4 + 1) * 112 + jn];
                float xv2 = sm_x[(q4 * 4 + 2) * 112 + jn];
                float xv3 = sm_x[(q4 * 4 + 3) * 112 + jn];
                #pragma unroll
                for (int pp = 0; pp < 8; ++pp) {
                    const float4 wq = wm4[pp * 16 + q4];
                    acc[pp] += xv0 * wq.x + xv1 * wq.y + xv2 * wq.z + xv3 * wq.w;
                }
            }
            #pragma unroll
            for (int pp = 0; pp < 8; ++pp)
                sm_t4[(j * 16 + pgrp * 8 + pp) * 17 + n] = acc[pp];
        }
    }
    __syncthreads();

    // ---- Phase C: conv, one thread per (l,p), full w-row, compile-time masks ----
    {
        const int p     = tid & 15;
        const int l_loc = tid >> 4;   // 0..15
        float acc[14];
        #pragma unroll
        for (int w = 0; w < 14; ++w) acc[w] = 0.f;

        #pragma unroll
        for (int j = 0; j < 8; ++j) {
            const float* row = &sm_t4[(j * 16 + p) * 17];
            float wt[9];
            #pragma unroll
            for (int t9 = 0; t9 < 9; ++t9)
                wt[t9] = sm_wc[l_loc * 72 + j * 9 + t9];
            #pragma unroll
            for (int w = 0; w < 14; ++w) {
                #pragma unroll
                for (int k1 = 0; k1 < 3; ++k1) {
                    #pragma unroll
                    for (int k2 = 0; k2 < 3; ++k2) {
                        const int n2 = w + k2 - 1;          // first-unfold window pos
                        const int ns = w + k1 + k2 - 2;     // composed source col
                        if (n2 >= 0 && n2 < 14 && ns >= 0 && ns < 14)
                            acc[w] += row[ns] * wt[k1 * 3 + k2];
                    }
                }
            }
        }

        const int h = (o == 13) ? 0 : (o + 1);   // roll +1 on H
        const int c = lh * 256 + tid;            // (lh*16+l_loc)*16 + p
        float* op = out + c * 196 + h * 14;
        #pragma unroll
        for (int w = 0; w < 14; ++w) op[w] = acc[w];
    }
}

extern "C" void kernel_launch(void* const* d_in, const int* in_sizes, int n_in,
                              void* d_out, int out_size, void* d_ws, size_t ws_size,
                              hipStream_t stream) {
    const float* x      = (const float*)d_in[0];
    const float* w_conv = (const float*)d_in[1];
    const float* w_mix  = (const float*)d_in[2];
    float* out = (float*)d_out;
    dim3 grid(14, 2, 1);
    fused_mix_unfold_conv<<<grid, 256, 0, stream>>>(x, w_conv, w_mix, out);
}

// Round 2
// 64.331 us; speedup vs baseline: 1.0422x; 1.0422x over previous
//
#include <hip/hip_runtime.h>

// out[l*16+p, (o+1)%14, w] = sum_{j,k1,k2} mask * t4[p,j,o, w+k1+k2-2] * w_conv[l,j,k1,k2]
//   mask: (0 <= w+k2-1 < 14) && (0 <= w+k1+k2-2 < 14)   (composed double-unfold padding)
// t4[p,j,o,n] = sum_q w_mix[p,q] * x[q*8+j, o, n]
//
// Grid (14 o-rows, 4 l-quarters) x 256 threads. Single barrier:
//   [stage w_conv quarter into LDS  +  Phase B: t4 partials via direct global x reads]
//   -> __syncthreads ->
//   [Phase C: conv, one thread per (l, p, w-half), compile-time padding masks]

#define T4_STRIDE 17  // 16-row pitch +1: p-lanes hit 16 distinct LDS banks

template <int WB>
__device__ __forceinline__ void conv_half(const float (*t4)[8 * 16 * T4_STRIDE],
                                          const float* __restrict__ wt,  // sm_wc + l_loc*72
                                          int p, float* __restrict__ op) {
    float acc[7];
#pragma unroll
    for (int w = 0; w < 7; ++w) acc[w] = 0.f;

#pragma unroll
    for (int j = 0; j < 8; ++j) {
        const float* r0 = &t4[0][(j * 16 + p) * T4_STRIDE];
        const float* r1 = &t4[1][(j * 16 + p) * T4_STRIDE];
        float r[14];
#pragma unroll
        for (int n = 0; n < 14; ++n) r[n] = r0[n] + r1[n];  // unused n DCE'd
        float w9[9];
#pragma unroll
        for (int t = 0; t < 9; ++t) w9[t] = wt[j * 9 + t];
#pragma unroll
        for (int w = 0; w < 7; ++w) {
            const int ww = WB + w;
#pragma unroll
            for (int k1 = 0; k1 < 3; ++k1) {
#pragma unroll
                for (int k2 = 0; k2 < 3; ++k2) {
                    const int n2 = ww + k2 - 1;       // first-unfold window pos
                    const int ns = ww + k1 + k2 - 2;  // composed source col
                    if (n2 >= 0 && n2 < 14 && ns >= 0 && ns < 14)
                        acc[w] += r[ns] * w9[k1 * 3 + k2];
                }
            }
        }
    }
#pragma unroll
    for (int w = 0; w < 7; ++w) op[w] = acc[w];
}

__global__ __launch_bounds__(256) void fused_mix_unfold_conv(
    const float* __restrict__ x,       // (512,14,14)
    const float* __restrict__ w_conv,  // (32,8,3,3)
    const float* __restrict__ w_mix,   // (16,64)
    float* __restrict__ out)           // (512,14,14)
{
    const int o   = blockIdx.x;  // pre-roll H row, 0..13
    const int lq  = blockIdx.y;  // l-quarter: l in [lq*8, lq*8+8)
    const int tid = threadIdx.x;

    __shared__ float sm_t4[2][8 * 16 * T4_STRIDE];  // [qh][j][p][n]
    __shared__ float sm_wc[8 * 72];                 // this block's quarter of w_conv

    // ---- stage w_conv quarter (no barrier needed before Phase B) ----
#pragma unroll
    for (int i = tid; i < 576; i += 256) sm_wc[i] = w_conv[lq * 576 + i];

    // ---- Phase B: t4 q-half partials, direct global x reads ----
    {
        const int qh = __builtin_amdgcn_readfirstlane(tid >> 7);  // wave-uniform 0/1
        const int jn = tid & 127;                                 // (j,n), valid < 112
        if (jn < 112) {
            const int j = jn / 14;
            const int n = jn - j * 14;
            float acc[16];
#pragma unroll
            for (int p = 0; p < 16; ++p) acc[p] = 0.f;

            const float* xb = x + (qh * 32 * 8 + j) * 196 + o * 14 + n;
            const float4* wm4 = (const float4*)w_mix + qh * 8;  // rows of 16 float4
#pragma unroll
            for (int q4 = 0; q4 < 8; ++q4) {
                const float xv0 = xb[(q4 * 4 + 0) * 1568];
                const float xv1 = xb[(q4 * 4 + 1) * 1568];
                const float xv2 = xb[(q4 * 4 + 2) * 1568];
                const float xv3 = xb[(q4 * 4 + 3) * 1568];
#pragma unroll
                for (int p = 0; p < 16; ++p) {
                    const float4 wq = wm4[p * 16 + q4];  // wave-uniform -> s_load
                    acc[p] += xv0 * wq.x + xv1 * wq.y + xv2 * wq.z + xv3 * wq.w;
                }
            }
#pragma unroll
            for (int p = 0; p < 16; ++p)
                sm_t4[qh][(j * 16 + p) * T4_STRIDE + n] = acc[p];
        }
    }
    __syncthreads();

    // ---- Phase C: conv, thread = (l_loc, p, w-half), wave-uniform half ----
    {
        const int p     = tid & 15;
        const int l_loc = (tid >> 4) & 7;
        const int wh    = __builtin_amdgcn_readfirstlane(tid >> 7);  // 0/1
        const int h     = (o == 13) ? 0 : (o + 1);                   // roll +1 on H
        const int c     = lq * 128 + (tid & 127);                    // (lq*8+l_loc)*16+p
        const float* wt = sm_wc + l_loc * 72;
        float* op = out + c * 196 + h * 14;
        if (wh == 0)
            conv_half<0>(sm_t4, wt, p, op);
        else
            conv_half<7>(sm_t4, wt, p, op + 7);
    }
}

extern "C" void kernel_launch(void* const* d_in, const int* in_sizes, int n_in,
                              void* d_out, int out_size, void* d_ws, size_t ws_size,
                              hipStream_t stream) {
    const float* x      = (const float*)d_in[0];
    const float* w_conv = (const float*)d_in[1];
    const float* w_mix  = (const float*)d_in[2];
    float* out = (float*)d_out;
    dim3 grid(14, 4, 1);
    fused_mix_unfold_conv<<<grid, 256, 0, stream>>>(x, w_conv, w_mix, out);
}